// Round 8
// baseline (69.307 us; speedup 1.0000x reference)
//
#include <hip/hip_runtime.h>

// Problem constants (match reference)
#define BB   8
#define CC   1024
#define TT   4096
#define HH   16
#define KK   31
#define PADD 15

#define RPT    16               // outputs per thread (256 threads * 16 = 4096 = T)
#define NRD    12               // ds_read_b128 per thread window (48 floats)
#define CHUNKS 1032             // 16B chunks per padded row: (4096+32)/4
#define NROWS  8                // batch rows per block (same channel -> same head)

typedef float floatx4 __attribute__((ext_vector_type(4)));

// XOR swizzle, verified by enumeration: p = q ^ ((q>>3)&7).
// Write pattern q=tid+256j and read pattern q=4*tid+c both hit each
// bank-quad exactly 2x per 16-lane phase (2-way = free, m136).
// Bijective on [0,1032): q>=1024 has (q>>3)&7==0 -> identity.
__device__ __forceinline__ int swz(int q) { return q ^ ((q >> 3) & 7); }

// --- softmax over the 31 taps of each of the 16 heads -> d_ws ---
__global__ void lwconv_softmax_w(const float* __restrict__ w, float* __restrict__ wsm) {
    int h = threadIdx.x;
    if (h < HH) {
        float buf[KK];
        float m = -1e30f;
        #pragma unroll
        for (int k = 0; k < KK; ++k) { buf[k] = w[h * KK + k]; m = fmaxf(m, buf[k]); }
        float s = 0.f;
        #pragma unroll
        for (int k = 0; k < KK; ++k) { buf[k] = expf(buf[k] - m); s += buf[k]; }
        float inv = 1.f / s;
        #pragma unroll
        for (int k = 0; k < KK; ++k) wsm[h * KK + k] = buf[k] * inv;
    }
}

// Load one padded row's chunk set for this thread (coalesced, zero-pad edges).
// Logical chunk q holds floats x[4q-16 .. 4q-13]; pad chunks q<4, q>1027.
__device__ __forceinline__ void load_row(const float* __restrict__ rowp, int tid,
                                         floatx4 rn[5]) {
    #pragma unroll
    for (int j = 0; j < 5; ++j) {
        const int q = tid + 256 * j;
        floatx4 v = (floatx4)0.f;
        if (j < 4 || tid < 8) {
            if (q >= 4 && q <= 1027)
                v = *reinterpret_cast<const floatx4*>(rowp + 4 * q - 16);
        }
        rn[j] = v;
    }
}

__device__ __forceinline__ void write_row(floatx4* __restrict__ b, int tid,
                                          const floatx4 rn[5]) {
    #pragma unroll
    for (int j = 0; j < 5; ++j) {
        const int q = tid + 256 * j;
        if (j < 4 || tid < 8) b[swz(q)] = rn[j];
    }
}

// --- main: one persistent block per channel; 8 batch rows, 2-deep LDS pipeline ---
// out[t] = bias + sum_k w[k] * x[t + k - 15]
__global__ __launch_bounds__(256, 4) void lwconv_main(const float* __restrict__ inp,
                                                      const float* __restrict__ wsm,
                                                      const float* __restrict__ bias,
                                                      float* __restrict__ out) {
    __shared__ floatx4 buf[2][CHUNKS];       // 33 KB -> 4 blocks/CU

    const int ch   = blockIdx.x;             // 0..1023
    const int head = ch >> 6;                 // 64 channels per head
    const int tid  = threadIdx.x;
    const int a    = tid << 4;                // first output index of this thread

    // uniform pre-softmaxed weights + bias -> SGPRs
    const float* wh = wsm + head * KK;
    float w[KK];
    #pragma unroll
    for (int k = 0; k < KK; ++k) w[k] = wh[k];
    const float bval = bias[head];

    // ---- prologue: fill both buffers (rows b=0,1) ----
    {
        floatx4 r0[5], r1[5];
        load_row(inp + (size_t)ch * TT, tid, r0);                       // b=0
        load_row(inp + ((size_t)CC + ch) * TT, tid, r1);                // b=1
        write_row(&buf[0][0], tid, r0);
        write_row(&buf[1][0], tid, r1);
    }
    asm volatile("s_waitcnt lgkmcnt(0)" ::: "memory");
    __builtin_amdgcn_s_barrier();

    #pragma unroll 1
    for (int it = 0; it < NROWS; ++it) {
        floatx4* bc = &buf[it & 1][0];

        // issue next-next row's loads early (fire-and-forget into regs)
        floatx4 rn[5];
        if (it < NROWS - 2)
            load_row(inp + ((size_t)(it + 2) * CC + ch) * TT, tid, rn);

        // window: 12 ds_read_b128 from swizzled layout (conflict-free)
        float xv[4 * NRD];
        #pragma unroll
        for (int c = 0; c < NRD; ++c) {
            floatx4 v = bc[swz(4 * tid + c)];
            #pragma unroll
            for (int e = 0; e < 4; ++e) xv[4 * c + e] = v[e];
        }
        asm volatile("s_waitcnt lgkmcnt(0)" ::: "memory");   // my reads landed
        __builtin_amdgcn_s_barrier();                        // barA: all reads done

        if (it < NROWS - 2)
            write_row(bc, tid, rn);                          // refill with row it+2
        asm volatile("s_waitcnt lgkmcnt(0)" ::: "memory");   // my writes landed
        __builtin_amdgcn_s_barrier();                        // barB: buffer refilled

        // compute row it entirely in registers, then store
        float acc[RPT];
        #pragma unroll
        for (int r = 0; r < RPT; ++r) acc[r] = bval;
        #pragma unroll
        for (int k = 0; k < KK; ++k) {
            #pragma unroll
            for (int r = 0; r < RPT; ++r)
                acc[r] = fmaf(xv[r + 1 + k], w[k], acc[r]);
        }

        float* orow = out + ((size_t)it * CC + ch) * TT + a;
        #pragma unroll
        for (int c2 = 0; c2 < RPT / 4; ++c2) {
            floatx4 o = { acc[4 * c2], acc[4 * c2 + 1],
                          acc[4 * c2 + 2], acc[4 * c2 + 3] };
            *reinterpret_cast<floatx4*>(orow + 4 * c2) = o;
        }
    }
}

extern "C" void kernel_launch(void* const* d_in, const int* in_sizes, int n_in,
                              void* d_out, int out_size, void* d_ws, size_t ws_size,
                              hipStream_t stream) {
    const float* inp    = (const float*)d_in[0];   // (B, C, T) fp32
    const float* weight = (const float*)d_in[1];   // (H, 1, K) fp32
    const float* bias   = (const float*)d_in[2];   // (H,) fp32
    float* out = (float*)d_out;
    float* wsm = (float*)d_ws;                     // H*K softmaxed weights

    lwconv_softmax_w<<<1, 64, 0, stream>>>(weight, wsm);

    lwconv_main<<<CC, 256, 0, stream>>>(inp, wsm, bias, out);   // 1024 blocks = 4/CU
}